// Round 9
// baseline (863.338 us; speedup 1.0000x reference)
//
#include <hip/hip_runtime.h>
#include <float.h>

// VQ: B=32, C=64, H=64, W=64, N_EMBED=512
#define C_DIM   64
#define K_CODES 512
#define HW_BITS 12              // HW = 4096
#define N_TOK   131072
#define TPB     64              // tokens per block
#define NW      8               // waves per block; wave w owns codes [64w, 64w+64)

typedef float f4 __attribute__((ext_vector_type(4)));

// Prep: transpose embed [C][K] -> eT [K][C], and norms[k] = ||e_k||^2.
__global__ __launch_bounds__(256) void vq_prep(const float* __restrict__ embed,
                                               float* __restrict__ eT,
                                               float* __restrict__ norms) {
    int k = blockIdx.x * blockDim.x + threadIdx.x;
    if (k >= K_CODES) return;
    float s = 0.f;
    #pragma unroll
    for (int c = 0; c < C_DIM; ++c) {
        float v = embed[c * K_CODES + k];   // coalesced across k
        eT[k * C_DIM + c] = v;
        s = fmaf(v, v, s);
    }
    norms[k] = s;
}

// lane = code: e-row in 16 named "+v"-pinned quads (VGPR-resident, re-pinned
// every iteration). x streams through the SCALAR pipe: one wave-uniform 16B
// s_load delivers channel c of 4 tokens; consumed as the SGPR operand of
// v_fma. Per group: 64 s_loads + 256 FMA. Zero per-lane loads in the loop.
__global__ __launch_bounds__(512, 2) void vq_main(const float* __restrict__ x,
                                                  const float* __restrict__ eT,
                                                  const float* __restrict__ norms,
                                                  float* __restrict__ out_qwg,
                                                  float* __restrict__ out_q,
                                                  float* __restrict__ out_ind) {
    __shared__ float sSc[NW][TPB];   // per-wave best score per token
    __shared__ int   sIx[NW][TPB];   // per-wave best code per token
    __shared__ int   gkL[TPB];       // merged winner per token

    const int tid  = threadIdx.x;
    const int lane = tid & 63;
    const int w    = tid >> 6;                 // wave id 0..7
    const int tok0 = blockIdx.x << 6;
    const int b    = tok0 >> HW_BITS;
    const int hw0  = tok0 & ((1 << HW_BITS) - 1);

    // ---- this lane's code row -> 16 named quads (64 VGPRs) ----
    const int code = (w << 6) + lane;
    const f4* er = (const f4*)(eT + ((size_t)code << 6));
    f4 e0 = er[0],  e1 = er[1],  e2 = er[2],  e3 = er[3];
    f4 e4 = er[4],  e5 = er[5],  e6 = er[6],  e7 = er[7];
    f4 e8 = er[8],  e9 = er[9],  e10 = er[10], e11 = er[11];
    f4 e12 = er[12], e13 = er[13], e14 = er[14], e15 = er[15];
    const float nrm = norms[code];

#define PIN_E()                                                        \
    asm volatile(""                                                    \
        : "+v"(e0), "+v"(e1), "+v"(e2), "+v"(e3),                      \
          "+v"(e4), "+v"(e5), "+v"(e6), "+v"(e7),                      \
          "+v"(e8), "+v"(e9), "+v"(e10), "+v"(e11),                    \
          "+v"(e12), "+v"(e13), "+v"(e14), "+v"(e15))
    PIN_E();

    // wave-uniform x base (f4 units): channel c, token-quad g -> index c*1024+g
    const f4* xg4 = (const f4*)(x + ((size_t)b << 18) + hw0);

    // ---- main loop: 16 groups of 4 tokens ----
    #pragma unroll 1
    for (int g = 0; g < 16; ++g) {
        PIN_E();   // re-pin each iteration: demotion would cost 64 copies/iter
        f4 acA = {0.f, 0.f, 0.f, 0.f};   // token 4g+0, chains c mod 4
        f4 acB = {0.f, 0.f, 0.f, 0.f};   // token 4g+1
        f4 acC = {0.f, 0.f, 0.f, 0.f};   // token 4g+2
        f4 acD = {0.f, 0.f, 0.f, 0.f};   // token 4g+3

        // channel c = 4Q+J: s_load x[c][4g..4g+3], fma into chain J.
        // Ascending c, chains = c mod 4: bit-identical to rounds 1-8.
#define CH(CIDX, EQ, CC)                                   \
        {                                                  \
            f4 fv = xg4[((CIDX) << 10) + g];               \
            acA.CC = fmaf(fv.x, EQ.CC, acA.CC);            \
            acB.CC = fmaf(fv.y, EQ.CC, acB.CC);            \
            acC.CC = fmaf(fv.z, EQ.CC, acC.CC);            \
            acD.CC = fmaf(fv.w, EQ.CC, acD.CC);            \
        }
        CH(0, e0, x)   CH(1, e0, y)   CH(2, e0, z)   CH(3, e0, w)
        CH(4, e1, x)   CH(5, e1, y)   CH(6, e1, z)   CH(7, e1, w)
        CH(8, e2, x)   CH(9, e2, y)   CH(10, e2, z)  CH(11, e2, w)
        CH(12, e3, x)  CH(13, e3, y)  CH(14, e3, z)  CH(15, e3, w)
        CH(16, e4, x)  CH(17, e4, y)  CH(18, e4, z)  CH(19, e4, w)
        CH(20, e5, x)  CH(21, e5, y)  CH(22, e5, z)  CH(23, e5, w)
        CH(24, e6, x)  CH(25, e6, y)  CH(26, e6, z)  CH(27, e6, w)
        CH(28, e7, x)  CH(29, e7, y)  CH(30, e7, z)  CH(31, e7, w)
        CH(32, e8, x)  CH(33, e8, y)  CH(34, e8, z)  CH(35, e8, w)
        CH(36, e9, x)  CH(37, e9, y)  CH(38, e9, z)  CH(39, e9, w)
        CH(40, e10, x) CH(41, e10, y) CH(42, e10, z) CH(43, e10, w)
        CH(44, e11, x) CH(45, e11, y) CH(46, e11, z) CH(47, e11, w)
        CH(48, e12, x) CH(49, e12, y) CH(50, e12, z) CH(51, e12, w)
        CH(52, e13, x) CH(53, e13, y) CH(54, e13, z) CH(55, e13, w)
        CH(56, e14, x) CH(57, e14, y) CH(58, e14, z) CH(59, e14, w)
        CH(60, e15, x) CH(61, e15, y) CH(62, e15, z) CH(63, e15, w)
#undef CH

        // score = fmaf(-2, (d0+d1)+(d2+d3), nrm) — same formula as r1-r8
#define RED(AC, TI)                                                        \
        {                                                                  \
            float sc_ = fmaf(-2.f, (AC.x + AC.y) + (AC.z + AC.w), nrm);    \
            float m_ = sc_;                                                \
            m_ = fminf(m_, __shfl_xor(m_, 32, 64));                        \
            m_ = fminf(m_, __shfl_xor(m_, 16, 64));                        \
            m_ = fminf(m_, __shfl_xor(m_, 8, 64));                         \
            m_ = fminf(m_, __shfl_xor(m_, 4, 64));                         \
            m_ = fminf(m_, __shfl_xor(m_, 2, 64));                         \
            m_ = fminf(m_, __shfl_xor(m_, 1, 64));                         \
            unsigned long long bal_ = __ballot(sc_ == m_);                 \
            int wl_ = __ffsll(bal_) - 1;  /* lowest lane = lowest code */  \
            if (lane == 0) {                                               \
                sSc[w][(g << 2) + TI] = m_;                                \
                sIx[w][(g << 2) + TI] = (w << 6) + wl_;                    \
            }                                                              \
        }
        RED(acA, 0) RED(acB, 1) RED(acC, 2) RED(acD, 3)
#undef RED
    }
#undef PIN_E
    __syncthreads();

    // ---- merge 8 wave-winners per token (ascending w, strict < = first-min) ----
    if (w == 0) {
        float gb = sSc[0][lane];
        int   gk = sIx[0][lane];
        #pragma unroll
        for (int ww = 1; ww < NW; ++ww) {
            float s = sSc[ww][lane];
            if (s < gb) { gb = s; gk = sIx[ww][lane]; }
        }
        gkL[lane] = gk;
        out_ind[tok0 + lane] = (float)gk;
    }
    __syncthreads();

    // ---- epilogue: wave w writes channels [8w, 8w+8) for token = lane ----
    {
        const int t  = lane;
        const int gk = gkL[t];
        const int c0 = w << 3;
        const float* qr = eT + ((size_t)gk << 6) + c0;     // per-lane gather, L2-hot
        f4 q0 = *(const f4*)(qr);
        f4 q1 = *(const f4*)(qr + 4);

        const float* xr = x + ((size_t)b << 18) + hw0 + t; // coalesced, L2-hot
        float fv[8];
        #pragma unroll
        for (int j = 0; j < 8; ++j) fv[j] = xr[(size_t)(c0 + j) << HW_BITS];

        float* o0 = out_qwg + ((size_t)b << 18) + hw0 + t;
        float* o1 = out_q   + ((size_t)b << 18) + hw0 + t;

        o0[(size_t)(c0 + 0) << HW_BITS] = fv[0] + (q0.x - fv[0]);
        o0[(size_t)(c0 + 1) << HW_BITS] = fv[1] + (q0.y - fv[1]);
        o0[(size_t)(c0 + 2) << HW_BITS] = fv[2] + (q0.z - fv[2]);
        o0[(size_t)(c0 + 3) << HW_BITS] = fv[3] + (q0.w - fv[3]);
        o0[(size_t)(c0 + 4) << HW_BITS] = fv[4] + (q1.x - fv[4]);
        o0[(size_t)(c0 + 5) << HW_BITS] = fv[5] + (q1.y - fv[5]);
        o0[(size_t)(c0 + 6) << HW_BITS] = fv[6] + (q1.z - fv[6]);
        o0[(size_t)(c0 + 7) << HW_BITS] = fv[7] + (q1.w - fv[7]);

        o1[(size_t)(c0 + 0) << HW_BITS] = q0.x;
        o1[(size_t)(c0 + 1) << HW_BITS] = q0.y;
        o1[(size_t)(c0 + 2) << HW_BITS] = q0.z;
        o1[(size_t)(c0 + 3) << HW_BITS] = q0.w;
        o1[(size_t)(c0 + 4) << HW_BITS] = q1.x;
        o1[(size_t)(c0 + 5) << HW_BITS] = q1.y;
        o1[(size_t)(c0 + 6) << HW_BITS] = q1.z;
        o1[(size_t)(c0 + 7) << HW_BITS] = q1.w;
    }
}

extern "C" void kernel_launch(void* const* d_in, const int* in_sizes, int n_in,
                              void* d_out, int out_size, void* d_ws, size_t ws_size,
                              hipStream_t stream) {
    const float* x     = (const float*)d_in[0];
    const float* embed = (const float*)d_in[1];

    float* out     = (float*)d_out;
    float* out_qwg = out;                       // 8388608 f32
    float* out_q   = out + (size_t)8388608;     // 8388608 f32
    float* out_ind = out + (size_t)16777216;    // 131072 f32

    float* eT    = (float*)d_ws;                // 512*64 f32 = 128 KB
    float* norms = eT + K_CODES * C_DIM;        // 512 f32

    vq_prep<<<2, 256, 0, stream>>>(embed, eT, norms);
    vq_main<<<N_TOK / TPB, 512, 0, stream>>>(x, eT, norms, out_qwg, out_q, out_ind);
}

// Round 10
// 276.111 us; speedup vs baseline: 3.1268x; 3.1268x over previous
//
#include <hip/hip_runtime.h>
#include <float.h>

// VQ: B=32, C=64, H=64, W=64, N_EMBED=512
#define C_DIM   64
#define K_CODES 512
#define HW_BITS 12            // HW = 4096
#define N_TOK   131072
#define KWIN    16            // k-rows per K$ window (4 KB) between barriers

typedef float f4 __attribute__((ext_vector_type(4)));

// Prep: transpose embed [C][K] -> eT [K][C], and norms[k] = ||e_k||^2.
__global__ __launch_bounds__(256) void vq_prep(const float* __restrict__ embed,
                                               float* __restrict__ eT,
                                               float* __restrict__ norms) {
    int k = blockIdx.x * blockDim.x + threadIdx.x;
    if (k >= K_CODES) return;
    float s = 0.f;
    #pragma unroll
    for (int c = 0; c < C_DIM; ++c) {
        float v = embed[c * K_CODES + k];   // coalesced across k
        eT[k * C_DIM + c] = v;
        s = fmaf(v, v, s);
    }
    norms[k] = s;
}

// Block = 256 threads = 4 waves = 256 DISTINCT tokens (lane=token). All waves
// sweep ALL 512 codes in the same ascending order, barrier-synced every KWIN
// rows so the block shares one K$ window: each e-row is one L2 fetch per
// block + 3 K$ hits. Argmin is purely per-lane (no shuffles / LDS merge).
// f is register-resident via the r8-proven named-quad + "+v" asm pin.
__global__ __launch_bounds__(256, 2) void vq_main(const float* __restrict__ x,
                                                  const float* __restrict__ eT,
                                                  const float* __restrict__ norms,
                                                  float* __restrict__ out_qwg,
                                                  float* __restrict__ out_q,
                                                  float* __restrict__ out_ind) {
    const int tok = (blockIdx.x << 8) + threadIdx.x;   // 256 tokens per block
    const int b   = tok >> HW_BITS;
    const int hw  = tok & ((1 << HW_BITS) - 1);

    const float* xb = x + ((size_t)b << 18) + hw;      // per-lane, coalesced

    // f in 16 named quads: f<Q> holds channels 4Q..4Q+3.
    f4 f0, f1, f2, f3, f4_, f5, f6, f7, f8, f9, f10, f11, f12, f13, f14, f15;
#define LOADF(V, Q)                                          \
    V = (f4){xb[(size_t)(4 * Q + 0) << HW_BITS],             \
             xb[(size_t)(4 * Q + 1) << HW_BITS],             \
             xb[(size_t)(4 * Q + 2) << HW_BITS],             \
             xb[(size_t)(4 * Q + 3) << HW_BITS]}
    LOADF(f0, 0);  LOADF(f1, 1);  LOADF(f2, 2);  LOADF(f3, 3);
    LOADF(f4_, 4); LOADF(f5, 5);  LOADF(f6, 6);  LOADF(f7, 7);
    LOADF(f8, 8);  LOADF(f9, 9);  LOADF(f10, 10); LOADF(f11, 11);
    LOADF(f12, 12); LOADF(f13, 13); LOADF(f14, 14); LOADF(f15, 15);
#undef LOADF

    // Residency pin (r8-proven form: once, after the loads, under (256,2)).
    asm volatile(""
        : "+v"(f0), "+v"(f1), "+v"(f2), "+v"(f3),
          "+v"(f4_), "+v"(f5), "+v"(f6), "+v"(f7),
          "+v"(f8), "+v"(f9), "+v"(f10), "+v"(f11),
          "+v"(f12), "+v"(f13), "+v"(f14), "+v"(f15));

    float best  = FLT_MAX;
    int   bestk = 0;

    #pragma unroll 1
    for (int kt = 0; kt < K_CODES; kt += KWIN) {
        #pragma unroll 2
        for (int kk = 0; kk < KWIN; ++kk) {
            const int    k = kt + kk;
            const float* e = eT + ((size_t)k << 6);   // uniform -> s_load path
            float d0 = 0.f, d1 = 0.f, d2 = 0.f, d3 = 0.f;
            // chains = c mod 4, ascending c: bit-identical to rounds 1-9
#define STEP(V, Q)                                \
            d0 = fmaf(V.x, e[4 * Q + 0], d0);     \
            d1 = fmaf(V.y, e[4 * Q + 1], d1);     \
            d2 = fmaf(V.z, e[4 * Q + 2], d2);     \
            d3 = fmaf(V.w, e[4 * Q + 3], d3);
            STEP(f0, 0)  STEP(f1, 1)  STEP(f2, 2)  STEP(f3, 3)
            STEP(f4_, 4) STEP(f5, 5)  STEP(f6, 6)  STEP(f7, 7)
            STEP(f8, 8)  STEP(f9, 9)  STEP(f10, 10) STEP(f11, 11)
            STEP(f12, 12) STEP(f13, 13) STEP(f14, 14) STEP(f15, 15)
#undef STEP
            float dot   = (d0 + d1) + (d2 + d3);
            float score = fmaf(-2.f, dot, norms[k]);   // same formula as r1-r9
            if (score < best) { best = score; bestk = k; }  // strict < = first min
        }
        __syncthreads();   // keep the 4 waves inside one K$ window
    }

    // ---- epilogue: per-lane, f reused from pinned registers ----
    const f4* eq = (const f4*)(eT + ((size_t)bestk << 6));   // per-lane gather
    float* o0 = out_qwg + ((size_t)b << 18) + hw;
    float* o1 = out_q   + ((size_t)b << 18) + hw;

#define EPI(J, V)                                                     \
    {                                                                 \
        f4 qv = eq[J];                                                \
        o0[(size_t)(4 * J + 0) << HW_BITS] = V.x + (qv.x - V.x);      \
        o0[(size_t)(4 * J + 1) << HW_BITS] = V.y + (qv.y - V.y);      \
        o0[(size_t)(4 * J + 2) << HW_BITS] = V.z + (qv.z - V.z);      \
        o0[(size_t)(4 * J + 3) << HW_BITS] = V.w + (qv.w - V.w);      \
        o1[(size_t)(4 * J + 0) << HW_BITS] = qv.x;                    \
        o1[(size_t)(4 * J + 1) << HW_BITS] = qv.y;                    \
        o1[(size_t)(4 * J + 2) << HW_BITS] = qv.z;                    \
        o1[(size_t)(4 * J + 3) << HW_BITS] = qv.w;                    \
    }
    EPI(0, f0)   EPI(1, f1)   EPI(2, f2)   EPI(3, f3)
    EPI(4, f4_)  EPI(5, f5)   EPI(6, f6)   EPI(7, f7)
    EPI(8, f8)   EPI(9, f9)   EPI(10, f10) EPI(11, f11)
    EPI(12, f12) EPI(13, f13) EPI(14, f14) EPI(15, f15)
#undef EPI

    out_ind[tok] = (float)bestk;
}

extern "C" void kernel_launch(void* const* d_in, const int* in_sizes, int n_in,
                              void* d_out, int out_size, void* d_ws, size_t ws_size,
                              hipStream_t stream) {
    const float* x     = (const float*)d_in[0];
    const float* embed = (const float*)d_in[1];

    float* out     = (float*)d_out;
    float* out_qwg = out;                       // 8388608 f32
    float* out_q   = out + (size_t)8388608;     // 8388608 f32
    float* out_ind = out + (size_t)16777216;    // 131072 f32

    float* eT    = (float*)d_ws;                // 512*64 f32 = 128 KB
    float* norms = eT + K_CODES * C_DIM;        // 512 f32

    vq_prep<<<2, 256, 0, stream>>>(embed, eT, norms);
    vq_main<<<N_TOK / 256, 256, 0, stream>>>(x, eT, norms, out_qwg, out_q, out_ind);
}